// Round 6
// baseline (1966.120 us; speedup 1.0000x reference)
//
#include <hip/hip_runtime.h>
#include <hip/hip_bf16.h>

// TKMDAttention on MI355X — round 6: split-bf16 MFMA GEMMs (hi/lo decomposition,
// 3x mfma_f32_16x16x32_bf16 per product, fragment-order X buffer, zero-LDS GEMM),
// spatial P stored bf16 (LDS 42.5->33.3 KB => 4 blocks/CU), cattn grid x4.
// Shapes: b=2, C=384, H=W=128, heads=8, ch=48, crop=8, N=64.
// windowstoimg: token n of window (wy,wx) -> y = wy*8+(wx>>1), x = (wx&1)*64+n.
// top-k rule (tie-exact): keep i for k iff a_i >= k-th largest (ref "a >= kth").

#define HW 16384
#define CDIM 384
#define NHEADS 8
#define CH 48

typedef __hip_bfloat16 bf16;
typedef __attribute__((ext_vector_type(8))) short short8;
typedef __attribute__((ext_vector_type(4))) float f32x4;

static __device__ __forceinline__ unsigned short f2bf_bits(float v) {
  bf16 b = __float2bfloat16(v);
  return __builtin_bit_cast(unsigned short, b);
}
static __device__ __forceinline__ float bfbits2f(unsigned short u) {
  return __bfloat162float(__builtin_bit_cast(bf16, u));
}

// ---------------- zero ----------------
__global__ void zero_f32(float* p, int n) {
  int i = blockIdx.x * 256 + threadIdx.x;
  if (i < n) p[i] = 0.f;
}

// ---- weight decompose: v = hi(bf16) + lo(bf16) ----
__global__ __launch_bounds__(256) void decomp_w(const float* __restrict__ src,
                                                unsigned short* __restrict__ h,
                                                unsigned short* __restrict__ l, int n) {
  int i = blockIdx.x * 256 + threadIdx.x;
  if (i >= n) return;
  float v = src[i];
  unsigned short hb = f2bf_bits(v);
  h[i] = hb;
  l[i] = f2bf_bits(v - bfbits2f(hb));
}

// ---- transpose src[384][16384] fp32 -> fragment-order bf16 hi/lo ----
// out index o = (ptile*12 + kc)*64 + lane ; element j of short8 holds
// src[kc*32 + (lane>>4)*8 + j][ptile*16 + (lane&15)]  (B-frag layout).
__global__ __launch_bounds__(256) void transpose_frag(const float* __restrict__ src,
                                                      short8* __restrict__ dh,
                                                      short8* __restrict__ dl) {
  const int o = blockIdx.x * 256 + threadIdx.x;  // [0, 786432)
  const int ptile = o / 768;
  const int rem = o - ptile * 768;
  const int kc = rem >> 6, lane = rem & 63;
  const int p = ptile * 16 + (lane & 15);
  const int kb = kc * 32 + (lane >> 4) * 8;
  short8 hh, ll;
#pragma unroll
  for (int j = 0; j < 8; j++) {
    float v = src[(size_t)(kb + j) * HW + p];
    unsigned short hb = f2bf_bits(v);
    hh[j] = (short)hb;
    ll[j] = (short)f2bf_bits(v - bfbits2f(hb));
  }
  dh[o] = hh;
  dl[o] = ll;
}

// ---- split-bf16 MFMA GEMM: Out[oc][p] = sum_k W[oc][k] X[k][p], K=384 ----
// Block: 64 oc x 128 p, 4 waves; wave owns 2 p-tiles x 4 oc-tiles (16x16 each).
// A-frags straight from global W (row-major, L2-hot); B-frags from frag-order Xtg.
__global__ __launch_bounds__(256, 2) void gemm_mfma(const unsigned short* __restrict__ Wh,
                                                    const unsigned short* __restrict__ Wl,
                                                    const short8* __restrict__ Xh,
                                                    const short8* __restrict__ Xl,
                                                    float* __restrict__ Out) {
  const int tid = threadIdx.x;
  const int wave = tid >> 6, lane = tid & 63;
  const int lm = lane & 15, lq = lane >> 4;
  const int p0 = blockIdx.x * 128;
  const int oc0 = blockIdx.y * 64;
  const int pt0 = blockIdx.x * 8 + wave * 2;
  f32x4 acc[4][2] = {};
#pragma unroll
  for (int kc = 0; kc < 12; kc++) {
    short8 ah[4], al[4], bh[2], bl[2];
#pragma unroll
    for (int mt = 0; mt < 4; mt++) {
      const size_t off = (size_t)(oc0 + mt * 16 + lm) * 384 + kc * 32 + lq * 8;
      ah[mt] = *reinterpret_cast<const short8*>(Wh + off);
      al[mt] = *reinterpret_cast<const short8*>(Wl + off);
    }
#pragma unroll
    for (int nt = 0; nt < 2; nt++) {
      const size_t idx = (size_t)((pt0 + nt) * 12 + kc) * 64 + lane;
      bh[nt] = Xh[idx];
      bl[nt] = Xl[idx];
    }
#pragma unroll
    for (int mt = 0; mt < 4; mt++)
#pragma unroll
      for (int nt = 0; nt < 2; nt++) {
        acc[mt][nt] = __builtin_amdgcn_mfma_f32_16x16x32_bf16(ah[mt], bh[nt], acc[mt][nt], 0, 0, 0);
        acc[mt][nt] = __builtin_amdgcn_mfma_f32_16x16x32_bf16(ah[mt], bl[nt], acc[mt][nt], 0, 0, 0);
        acc[mt][nt] = __builtin_amdgcn_mfma_f32_16x16x32_bf16(al[mt], bh[nt], acc[mt][nt], 0, 0, 0);
      }
  }
  // D layout: col(n) = lane&15, row(m) = (lane>>4)*4 + reg
#pragma unroll
  for (int mt = 0; mt < 4; mt++)
#pragma unroll
    for (int nt = 0; nt < 2; nt++)
#pragma unroll
      for (int r = 0; r < 4; r++) {
        const int oc = oc0 + mt * 16 + lq * 4 + r;
        const int p = p0 + (wave * 2 + nt) * 16 + lm;
        Out[(size_t)oc * HW + p] = acc[mt][nt][r];
      }
}

// ---- depthwise 3x3 pad1, 384 channels (one qkv third) ----
__global__ __launch_bounds__(256) void dwconv3(const float* __restrict__ A,
                                               const float* __restrict__ wdw,
                                               float* __restrict__ Bq) {
  const int idx = blockIdx.x * 256 + threadIdx.x;
  const int x = idx & 127;
  const int y = (idx >> 7) & 127;
  const int ch = idx >> 14;
  float w[9];
#pragma unroll
  for (int t = 0; t < 9; t++) w[t] = wdw[ch * 9 + t];
  const float* Ap = A + (size_t)ch * HW;
  float acc = 0.f;
#pragma unroll
  for (int ky = 0; ky < 3; ky++) {
    const int yy = y + ky - 1;
    if (yy < 0 || yy > 127) continue;
#pragma unroll
    for (int kx = 0; kx < 3; kx++) {
      const int xx = x + kx - 1;
      if (xx < 0 || xx > 127) continue;
      acc += w[ky * 3 + kx] * Ap[yy * 128 + xx];
    }
  }
  Bq[idx] = acc;
}

// ---- per-channel 1/max(||row||,1e-12), rows 0..767 (q then k) ----
__global__ __launch_bounds__(256) void chan_norms(const float* __restrict__ Bq,
                                                  float* __restrict__ inv) {
  const int row = blockIdx.x;
  const size_t base = (size_t)row * HW;
  const int tid = threadIdx.x;
  float s = 0.f;
  for (int p = tid; p < HW; p += 256) {
    float v = Bq[base + p];
    s += v * v;
  }
  for (int o = 32; o; o >>= 1) s += __shfl_xor(s, o);
  __shared__ float red[4];
  if ((tid & 63) == 0) red[tid >> 6] = s;
  __syncthreads();
  if (tid == 0) {
    float t = red[0] + red[1] + red[2] + red[3];
    inv[row] = 1.f / fmaxf(sqrtf(t), 1e-12f);
  }
}

// ---- channel-attn raw logits, 64 chunks of 256, atomic accumulate ----
__global__ __launch_bounds__(256) void cattn_partial(const float* __restrict__ Bq,
                                                     float* __restrict__ raw) {
  __shared__ __align__(16) float qs[48][65];
  __shared__ __align__(16) float ks2[48][65];
  const int tid = threadIdx.x;
  const int chunk = blockIdx.x, h = blockIdx.y;
  const int p0 = chunk * 256;
  const int tx = tid & 15, ty = tid >> 4;
  const size_t qbase = (size_t)(h * CH) * HW;
  const size_t kbase = (size_t)(CDIM + h * CH) * HW;
  float acc[3][3] = {};
  for (int pp = 0; pp < 256; pp += 64) {
    for (int s = tid; s < 48 * 64; s += 256) {
      int cc = s >> 6, pl = s & 63;
      qs[cc][pl] = Bq[qbase + (size_t)cc * HW + p0 + pp + pl];
      ks2[cc][pl] = Bq[kbase + (size_t)cc * HW + p0 + pp + pl];
    }
    __syncthreads();
    for (int pl = 0; pl < 64; pl++) {
      float qv[3], kv[3];
#pragma unroll
      for (int ii = 0; ii < 3; ii++) qv[ii] = qs[ty * 3 + ii][pl];
#pragma unroll
      for (int jj = 0; jj < 3; jj++) kv[jj] = ks2[tx * 3 + jj][pl];
#pragma unroll
      for (int ii = 0; ii < 3; ii++)
#pragma unroll
        for (int jj = 0; jj < 3; jj++) acc[ii][jj] += qv[ii] * kv[jj];
    }
    __syncthreads();
  }
  float* rp = raw + (size_t)h * 2304;
#pragma unroll
  for (int ii = 0; ii < 3; ii++)
#pragma unroll
    for (int jj = 0; jj < 3; jj++)
      atomicAdd(&rp[(ty * 3 + ii) * 48 + tx * 3 + jj], acc[ii][jj]);
}

// ---- channel masked-softmax combine -> W48 ----
__global__ __launch_bounds__(64) void chan_softmax(
    const float* __restrict__ raw, const float* __restrict__ inv,
    const float* __restrict__ temp, const float* __restrict__ a1,
    const float* __restrict__ a2, const float* __restrict__ a3,
    const float* __restrict__ a4, float* __restrict__ W48) {
  const int blk = blockIdx.x;  // h*48 + i
  const int i = blk % 48;
  const int h = blk / 48;
  const int lane = threadIdx.x;
  const float t = temp[h];
  float a = -3.0e38f;
  if (lane < 48) {
    float r = raw[(size_t)blk * 48 + lane];
    a = t * inv[h * CH + i] * inv[CDIM + h * CH + lane] * r;
  }
  float m = a;
  for (int o = 32; o; o >>= 1) m = fmaxf(m, __shfl_xor(m, o));
  float e = (lane < 48) ? expf(a - m) : 0.f;
  int gt = 0;
  for (int j = 0; j < 48; j++) {
    float vj = __shfl(a, j);
    gt += (vj > a) ? 1 : 0;
  }
  const int ksel[4] = {24, 32, 36, 38};
  const float wts[4] = {a1[0], a2[0], a3[0], a4[0]};
  float coef = 0.f;
#pragma unroll
  for (int kk = 0; kk < 4; kk++) {
    float sel = (gt < ksel[kk]) ? e : 0.f;
    for (int o = 32; o; o >>= 1) sel += __shfl_xor(sel, o);
    if (gt < ksel[kk]) coef += wts[kk] / sel;
  }
  if (lane < 48) W48[(size_t)blk * 48 + lane] = e * coef;
}

// ---- channel out: Cbuf[h*48+i, p] = sum_j W48[h][i,j]*v[j,p] ----
__global__ __launch_bounds__(256) void cout_kernel(const float* __restrict__ W48,
                                                   const float* __restrict__ Bq,
                                                   float* __restrict__ Cbuf) {
  __shared__ __align__(16) float Wl[2304];
  const int tid = threadIdx.x;
  const int h = blockIdx.y;
  const float* wsrc = W48 + (size_t)h * 2304;
  for (int s = tid; s < 2304; s += 256) Wl[s] = wsrc[s];
  __syncthreads();
  const int p = blockIdx.x * 64 + (tid & 63);
  const int ig = tid >> 6;
  const float* vbase = Bq + (size_t)(2 * CDIM + h * CH) * HW + p;
  float acc[12] = {};
  for (int j0 = 0; j0 < 48; j0 += 4) {
    float vj[4];
#pragma unroll
    for (int q = 0; q < 4; q++) vj[q] = vbase[(size_t)(j0 + q) * HW];
#pragma unroll
    for (int ii = 0; ii < 12; ii++) {
      const float4 w4 = *reinterpret_cast<const float4*>(&Wl[(ig * 12 + ii) * 48 + j0]);
      acc[ii] += w4.x * vj[0] + w4.y * vj[1] + w4.z * vj[2] + w4.w * vj[3];
    }
  }
  float* obase = Cbuf + (size_t)(h * CH + ig * 12) * HW + p;
#pragma unroll
  for (int ii = 0; ii < 12; ii++) obase[(size_t)ii * HW] = acc[ii];
}

// ---- window attention; P stored bf16 (LDS 33.3 KB => 4 blocks/CU) ----
__global__ __launch_bounds__(256) void spatial_kernel(
    const float* __restrict__ Bq, const float* __restrict__ temp,
    const float* __restrict__ a1, const float* __restrict__ a2,
    const float* __restrict__ a3, const float* __restrict__ a4,
    float* __restrict__ Cbuf) {
  __shared__ float kL[64 * 49];
  __shared__ float qvL[64 * 49];
  __shared__ bf16 Pld[64 * 66];
  __shared__ float invqS[64], invkS[64];
  const int wid = blockIdx.x;  // head*256 + wy*16 + wx
  const int wx = wid & 15, wy = (wid >> 4) & 15;
  const int head = wid >> 8;
  const int tid = threadIdx.x;
  for (int s = tid; s < 2 * 3072; s += 256) {
    const int t = s / 3072;
    const int r = s % 3072;
    const int cc = r >> 6, n = r & 63;
    const int y = wy * 8 + (n >> 3), x = wx * 8 + (n & 7);
    const int chan = t * CDIM + head * CH + cc;
    (t ? kL : qvL)[n * 49 + cc] = Bq[(size_t)chan * HW + y * 128 + x];
  }
  __syncthreads();
  if (tid < 128) {
    const int t = tid >> 6, n = tid & 63;
    const float* src = t ? kL : qvL;
    float s = 0.f;
    for (int cc = 0; cc < 48; cc++) {
      float v = src[n * 49 + cc];
      s += v * v;
    }
    float iv = 1.f / fmaxf(sqrtf(s), 1e-12f);
    if (t) invkS[n] = iv; else invqS[n] = iv;
  }
  __syncthreads();
  const float tscale = temp[wx & 7];
  const float wts[4] = {a1[0], a2[0], a3[0], a4[0]};
  const int ksel[4] = {32, 42, 48, 51};
  const int lane = tid & 63, w = tid >> 6;
  const float ik = invkS[lane];
  for (int g = 0; g < 4; g++) {
    const int n0 = w * 16 + g * 4;
    float accr[4] = {0.f, 0.f, 0.f, 0.f};
    for (int cc = 0; cc < 48; cc++) {
      const float kv = kL[lane * 49 + cc];
#pragma unroll
      for (int r = 0; r < 4; r++) accr[r] += qvL[(n0 + r) * 49 + cc] * kv;
    }
#pragma unroll
    for (int r = 0; r < 4; r++) {
      const int n = n0 + r;
      const float a = accr[r] * invqS[n] * ik * tscale;
      float s = a;  // bitonic ascending sort across 64 lanes
#pragma unroll
      for (int k = 2; k <= 64; k <<= 1) {
#pragma unroll
        for (int j = k >> 1; j > 0; j >>= 1) {
          const float o = __shfl_xor(s, j);
          const bool up = ((lane & k) == 0);
          const bool lower = ((lane & j) == 0);
          const float mn = fminf(s, o), mx = fmaxf(s, o);
          s = (lower == up) ? mn : mx;
        }
      }
      const float m = __shfl(s, 63);
      const float e = expf(a - m);
      float coef = 0.f;
#pragma unroll
      for (int kk = 0; kk < 4; kk++) {
        const float tk = __shfl(s, 64 - ksel[kk]);
        const bool keep = (a >= tk);
        float sel = keep ? e : 0.f;
        for (int o = 32; o; o >>= 1) sel += __shfl_xor(sel, o);
        if (keep) coef += wts[kk] / sel;
      }
      Pld[n * 66 + lane] = __float2bfloat16(e * coef);
    }
  }
  __syncthreads();
  // load v over q (dead)
  for (int s = tid; s < 3072; s += 256) {
    const int cc = s >> 6, n = s & 63;
    const int y = wy * 8 + (n >> 3), x = wx * 8 + (n & 7);
    const int chan = 2 * CDIM + head * CH + cc;
    qvL[n * 49 + cc] = Bq[(size_t)chan * HW + y * 128 + x];
  }
  __syncthreads();
  const int n = lane, cg = w;
  float acc[12] = {};
  for (int mm = 0; mm < 64; mm++) {
    const float pv = __bfloat162float(Pld[n * 66 + mm]);
#pragma unroll
    for (int ci = 0; ci < 12; ci++) acc[ci] += pv * qvL[mm * 49 + cg + ci * 4];
  }
  const int y_out = wy * 8 + (wx >> 1);
  const int x_out = (wx & 1) * 64 + n;
#pragma unroll
  for (int ci = 0; ci < 12; ci++) {
    const int cc = cg + ci * 4;
    const size_t idx = ((size_t)(head * CH + cc) * 128 + y_out) * 128 + x_out;
    Cbuf[idx] += acc[ci];
  }
}

// ---------------- launch ----------------
extern "C" void kernel_launch(void* const* d_in, const int* in_sizes, int n_in,
                              void* d_out, int out_size, void* d_ws, size_t ws_size,
                              hipStream_t stream) {
  const float* x = (const float*)d_in[0];
  const float* w_qkv = (const float*)d_in[1];
  const float* w_dw = (const float*)d_in[2];
  const float* w_proj = (const float*)d_in[3];
  const float* temp = (const float*)d_in[4];
  const float* a1 = (const float*)d_in[5];
  const float* a2 = (const float*)d_in[6];
  const float* a3 = (const float*)d_in[7];
  const float* a4 = (const float*)d_in[8];
  float* out = (float*)d_out;

  // ws layout (bytes):
  //   [0,        73728)   cattn_raw f32
  //   [73728,   147456)   W48 f32
  //   [147456,  150528)   inv f32 (768)
  //   [151040,  1035776)  wqkv_h  bf16 bits (1152x384)
  //   [1035776, 1920512)  wqkv_l
  //   [1920512, 2215424)  wproj_h (384x384)
  //   [2215424, 2510336)  wproj_l
  //   [2510848, 78008320) Bq f32 (1152x16384) = 75.5 MB
  //     Xtg hi/lo (12.58+12.58 MB) lives in Bq's v-third during qkv phase;
  //     Ctg hi/lo lives in Bq's q-third during proj phase.
  // Peak 78.0 MB (<= proven 89.4 MB).
  char* ws = (char*)d_ws;
  float* cattn_raw = (float*)ws;
  float* W48 = (float*)(ws + 73728);
  float* inv = (float*)(ws + 147456);
  unsigned short* wqkv_h = (unsigned short*)(ws + 151040);
  unsigned short* wqkv_l = (unsigned short*)(ws + 1035776);
  unsigned short* wproj_h = (unsigned short*)(ws + 1920512);
  unsigned short* wproj_l = (unsigned short*)(ws + 2215424);
  float* Bq = (float*)(ws + 2510848);
  short8* Xtgh = (short8*)(ws + 2510848 + (size_t)2 * CDIM * HW * 4);
  short8* Xtgl = (short8*)(ws + 2510848 + (size_t)2 * CDIM * HW * 4 + 12582912);
  short8* Ctgh = (short8*)(ws + 2510848);
  short8* Ctgl = (short8*)(ws + 2510848 + 12582912);

  decomp_w<<<(3 * CDIM * CDIM + 255) / 256, 256, 0, stream>>>(w_qkv, wqkv_h, wqkv_l,
                                                              3 * CDIM * CDIM);
  decomp_w<<<(CDIM * CDIM + 255) / 256, 256, 0, stream>>>(w_proj, wproj_h, wproj_l,
                                                          CDIM * CDIM);

  for (int b = 0; b < 2; b++) {
    const float* xb = x + (size_t)b * CDIM * HW;
    float* ob = out + (size_t)b * CDIM * HW;  // scratch (conv1 out / Cbuf) then final

    zero_f32<<<(NHEADS * 48 * 48 + 255) / 256, 256, 0, stream>>>(cattn_raw, NHEADS * 48 * 48);

    // x -> fragment-order hi/lo (in Bq v-third, dead until dwconv t=2)
    transpose_frag<<<3072, 256, 0, stream>>>(xb, Xtgh, Xtgl);
    for (int t = 0; t < 3; t++) {
      gemm_mfma<<<dim3(HW / 128, CDIM / 64), 256, 0, stream>>>(
          wqkv_h + (size_t)t * CDIM * CDIM, wqkv_l + (size_t)t * CDIM * CDIM,
          Xtgh, Xtgl, ob);
      dwconv3<<<(CDIM * HW) / 256, 256, 0, stream>>>(
          ob, w_dw + (size_t)t * CDIM * 9, Bq + (size_t)t * CDIM * HW);
    }

    chan_norms<<<2 * CDIM, 256, 0, stream>>>(Bq, inv);
    cattn_partial<<<dim3(64, NHEADS), 256, 0, stream>>>(Bq, cattn_raw);
    chan_softmax<<<NHEADS * 48, 64, 0, stream>>>(cattn_raw, inv, temp, a1, a2, a3, a4, W48);
    cout_kernel<<<dim3(HW / 64, NHEADS), 256, 0, stream>>>(W48, Bq, ob);
    spatial_kernel<<<NHEADS * 256, 256, 0, stream>>>(Bq, temp, a1, a2, a3, a4, ob);

    // proj: Cbuf(=ob) -> frag-order hi/lo in Bq q-third (dead), gemm -> ob
    transpose_frag<<<3072, 256, 0, stream>>>(ob, Ctgh, Ctgl);
    gemm_mfma<<<dim3(HW / 128, CDIM / 64), 256, 0, stream>>>(wproj_h, wproj_l,
                                                             Ctgh, Ctgl, ob);
  }

  (void)in_sizes; (void)n_in; (void)out_size; (void)ws_size;
}

// Round 7
// 1388.295 us; speedup vs baseline: 1.4162x; 1.4162x over previous
//
#include <hip/hip_runtime.h>
#include <hip/hip_bf16.h>

// TKMDAttention on MI355X — round 7: round-6 (split-bf16 MFMA GEMMs) with the
// cattn atomic-contention regression fixed: private per-chunk partials + small
// reduce kernel (no device-scope atomics at all).
// Shapes: b=2, C=384, H=W=128, heads=8, ch=48, crop=8, N=64.
// windowstoimg: token n of window (wy,wx) -> y = wy*8+(wx>>1), x = (wx&1)*64+n.
// top-k rule (tie-exact): keep i for k iff a_i >= k-th largest (ref "a >= kth").

#define HW 16384
#define CDIM 384
#define NHEADS 8
#define CH 48

typedef __hip_bfloat16 bf16;
typedef __attribute__((ext_vector_type(8))) short short8;
typedef __attribute__((ext_vector_type(4))) float f32x4;

static __device__ __forceinline__ unsigned short f2bf_bits(float v) {
  bf16 b = __float2bfloat16(v);
  return __builtin_bit_cast(unsigned short, b);
}
static __device__ __forceinline__ float bfbits2f(unsigned short u) {
  return __bfloat162float(__builtin_bit_cast(bf16, u));
}

// ---- weight decompose: v = hi(bf16) + lo(bf16) ----
__global__ __launch_bounds__(256) void decomp_w(const float* __restrict__ src,
                                                unsigned short* __restrict__ h,
                                                unsigned short* __restrict__ l, int n) {
  int i = blockIdx.x * 256 + threadIdx.x;
  if (i >= n) return;
  float v = src[i];
  unsigned short hb = f2bf_bits(v);
  h[i] = hb;
  l[i] = f2bf_bits(v - bfbits2f(hb));
}

// ---- transpose src[384][16384] fp32 -> fragment-order bf16 hi/lo ----
// out index o = (ptile*12 + kc)*64 + lane ; element j of short8 holds
// src[kc*32 + (lane>>4)*8 + j][ptile*16 + (lane&15)]  (B-frag layout).
__global__ __launch_bounds__(256) void transpose_frag(const float* __restrict__ src,
                                                      short8* __restrict__ dh,
                                                      short8* __restrict__ dl) {
  const int o = blockIdx.x * 256 + threadIdx.x;  // [0, 786432)
  const int ptile = o / 768;
  const int rem = o - ptile * 768;
  const int kc = rem >> 6, lane = rem & 63;
  const int p = ptile * 16 + (lane & 15);
  const int kb = kc * 32 + (lane >> 4) * 8;
  short8 hh, ll;
#pragma unroll
  for (int j = 0; j < 8; j++) {
    float v = src[(size_t)(kb + j) * HW + p];
    unsigned short hb = f2bf_bits(v);
    hh[j] = (short)hb;
    ll[j] = (short)f2bf_bits(v - bfbits2f(hb));
  }
  dh[o] = hh;
  dl[o] = ll;
}

// ---- split-bf16 MFMA GEMM: Out[oc][p] = sum_k W[oc][k] X[k][p], K=384 ----
// Block: 64 oc x 128 p, 4 waves; wave owns 2 p-tiles x 4 oc-tiles (16x16 each).
__global__ __launch_bounds__(256, 2) void gemm_mfma(const unsigned short* __restrict__ Wh,
                                                    const unsigned short* __restrict__ Wl,
                                                    const short8* __restrict__ Xh,
                                                    const short8* __restrict__ Xl,
                                                    float* __restrict__ Out) {
  const int tid = threadIdx.x;
  const int wave = tid >> 6, lane = tid & 63;
  const int lm = lane & 15, lq = lane >> 4;
  const int p0 = blockIdx.x * 128;
  const int oc0 = blockIdx.y * 64;
  const int pt0 = blockIdx.x * 8 + wave * 2;
  f32x4 acc[4][2] = {};
#pragma unroll
  for (int kc = 0; kc < 12; kc++) {
    short8 ah[4], al[4], bh[2], bl[2];
#pragma unroll
    for (int mt = 0; mt < 4; mt++) {
      const size_t off = (size_t)(oc0 + mt * 16 + lm) * 384 + kc * 32 + lq * 8;
      ah[mt] = *reinterpret_cast<const short8*>(Wh + off);
      al[mt] = *reinterpret_cast<const short8*>(Wl + off);
    }
#pragma unroll
    for (int nt = 0; nt < 2; nt++) {
      const size_t idx = (size_t)((pt0 + nt) * 12 + kc) * 64 + lane;
      bh[nt] = Xh[idx];
      bl[nt] = Xl[idx];
    }
#pragma unroll
    for (int mt = 0; mt < 4; mt++)
#pragma unroll
      for (int nt = 0; nt < 2; nt++) {
        acc[mt][nt] = __builtin_amdgcn_mfma_f32_16x16x32_bf16(ah[mt], bh[nt], acc[mt][nt], 0, 0, 0);
        acc[mt][nt] = __builtin_amdgcn_mfma_f32_16x16x32_bf16(ah[mt], bl[nt], acc[mt][nt], 0, 0, 0);
        acc[mt][nt] = __builtin_amdgcn_mfma_f32_16x16x32_bf16(al[mt], bh[nt], acc[mt][nt], 0, 0, 0);
      }
  }
  // D layout: col(n) = lane&15, row(m) = (lane>>4)*4 + reg
#pragma unroll
  for (int mt = 0; mt < 4; mt++)
#pragma unroll
    for (int nt = 0; nt < 2; nt++)
#pragma unroll
      for (int r = 0; r < 4; r++) {
        const int oc = oc0 + mt * 16 + lq * 4 + r;
        const int p = p0 + (wave * 2 + nt) * 16 + lm;
        Out[(size_t)oc * HW + p] = acc[mt][nt][r];
      }
}

// ---- depthwise 3x3 pad1, 384 channels (one qkv third) ----
__global__ __launch_bounds__(256) void dwconv3(const float* __restrict__ A,
                                               const float* __restrict__ wdw,
                                               float* __restrict__ Bq) {
  const int idx = blockIdx.x * 256 + threadIdx.x;
  const int x = idx & 127;
  const int y = (idx >> 7) & 127;
  const int ch = idx >> 14;
  float w[9];
#pragma unroll
  for (int t = 0; t < 9; t++) w[t] = wdw[ch * 9 + t];
  const float* Ap = A + (size_t)ch * HW;
  float acc = 0.f;
#pragma unroll
  for (int ky = 0; ky < 3; ky++) {
    const int yy = y + ky - 1;
    if (yy < 0 || yy > 127) continue;
#pragma unroll
    for (int kx = 0; kx < 3; kx++) {
      const int xx = x + kx - 1;
      if (xx < 0 || xx > 127) continue;
      acc += w[ky * 3 + kx] * Ap[yy * 128 + xx];
    }
  }
  Bq[idx] = acc;
}

// ---- per-channel 1/max(||row||,1e-12), rows 0..767 (q then k) ----
__global__ __launch_bounds__(256) void chan_norms(const float* __restrict__ Bq,
                                                  float* __restrict__ inv) {
  const int row = blockIdx.x;
  const size_t base = (size_t)row * HW;
  const int tid = threadIdx.x;
  float s = 0.f;
  for (int p = tid; p < HW; p += 256) {
    float v = Bq[base + p];
    s += v * v;
  }
  for (int o = 32; o; o >>= 1) s += __shfl_xor(s, o);
  __shared__ float red[4];
  if ((tid & 63) == 0) red[tid >> 6] = s;
  __syncthreads();
  if (tid == 0) {
    float t = red[0] + red[1] + red[2] + red[3];
    inv[row] = 1.f / fmaxf(sqrtf(t), 1e-12f);
  }
}

// ---- channel-attn partial logits: NO atomics, private slot per (chunk,head) ----
__global__ __launch_bounds__(256) void cattn_partial(const float* __restrict__ Bq,
                                                     float* __restrict__ part) {
  __shared__ __align__(16) float qs[48][65];
  __shared__ __align__(16) float ks2[48][65];
  const int tid = threadIdx.x;
  const int chunk = blockIdx.x, h = blockIdx.y;  // 16 chunks of 1024
  const int p0 = chunk * 1024;
  const int tx = tid & 15, ty = tid >> 4;
  const size_t qbase = (size_t)(h * CH) * HW;
  const size_t kbase = (size_t)(CDIM + h * CH) * HW;
  float acc[3][3] = {};
  for (int pp = 0; pp < 1024; pp += 64) {
    for (int s = tid; s < 48 * 64; s += 256) {
      int cc = s >> 6, pl = s & 63;
      qs[cc][pl] = Bq[qbase + (size_t)cc * HW + p0 + pp + pl];
      ks2[cc][pl] = Bq[kbase + (size_t)cc * HW + p0 + pp + pl];
    }
    __syncthreads();
#pragma unroll 4
    for (int pl = 0; pl < 64; pl++) {
      float qv[3], kv[3];
#pragma unroll
      for (int ii = 0; ii < 3; ii++) qv[ii] = qs[ty * 3 + ii][pl];
#pragma unroll
      for (int jj = 0; jj < 3; jj++) kv[jj] = ks2[tx * 3 + jj][pl];
#pragma unroll
      for (int ii = 0; ii < 3; ii++)
#pragma unroll
        for (int jj = 0; jj < 3; jj++) acc[ii][jj] += qv[ii] * kv[jj];
    }
    __syncthreads();
  }
  float* rp = part + (size_t)(h * 16 + chunk) * 2304;
#pragma unroll
  for (int ii = 0; ii < 3; ii++)
#pragma unroll
    for (int jj = 0; jj < 3; jj++)
      rp[(ty * 3 + ii) * 48 + tx * 3 + jj] = acc[ii][jj];
}

// ---- reduce 16 partials per head -> raw[h][48*48] ----
__global__ __launch_bounds__(256) void cattn_reduce(const float* __restrict__ part,
                                                    float* __restrict__ raw) {
  const int h = blockIdx.x;
  for (int idx = threadIdx.x; idx < 2304; idx += 256) {
    float s = 0.f;
#pragma unroll
    for (int c = 0; c < 16; c++) s += part[(size_t)(h * 16 + c) * 2304 + idx];
    raw[(size_t)h * 2304 + idx] = s;
  }
}

// ---- channel masked-softmax combine -> W48 ----
__global__ __launch_bounds__(64) void chan_softmax(
    const float* __restrict__ raw, const float* __restrict__ inv,
    const float* __restrict__ temp, const float* __restrict__ a1,
    const float* __restrict__ a2, const float* __restrict__ a3,
    const float* __restrict__ a4, float* __restrict__ W48) {
  const int blk = blockIdx.x;  // h*48 + i
  const int i = blk % 48;
  const int h = blk / 48;
  const int lane = threadIdx.x;
  const float t = temp[h];
  float a = -3.0e38f;
  if (lane < 48) {
    float r = raw[(size_t)blk * 48 + lane];
    a = t * inv[h * CH + i] * inv[CDIM + h * CH + lane] * r;
  }
  float m = a;
  for (int o = 32; o; o >>= 1) m = fmaxf(m, __shfl_xor(m, o));
  float e = (lane < 48) ? expf(a - m) : 0.f;
  int gt = 0;
  for (int j = 0; j < 48; j++) {
    float vj = __shfl(a, j);
    gt += (vj > a) ? 1 : 0;
  }
  const int ksel[4] = {24, 32, 36, 38};
  const float wts[4] = {a1[0], a2[0], a3[0], a4[0]};
  float coef = 0.f;
#pragma unroll
  for (int kk = 0; kk < 4; kk++) {
    float sel = (gt < ksel[kk]) ? e : 0.f;
    for (int o = 32; o; o >>= 1) sel += __shfl_xor(sel, o);
    if (gt < ksel[kk]) coef += wts[kk] / sel;
  }
  if (lane < 48) W48[(size_t)blk * 48 + lane] = e * coef;
}

// ---- channel out: Cbuf[h*48+i, p] = sum_j W48[h][i,j]*v[j,p] ----
__global__ __launch_bounds__(256) void cout_kernel(const float* __restrict__ W48,
                                                   const float* __restrict__ Bq,
                                                   float* __restrict__ Cbuf) {
  __shared__ __align__(16) float Wl[2304];
  const int tid = threadIdx.x;
  const int h = blockIdx.y;
  const float* wsrc = W48 + (size_t)h * 2304;
  for (int s = tid; s < 2304; s += 256) Wl[s] = wsrc[s];
  __syncthreads();
  const int p = blockIdx.x * 64 + (tid & 63);
  const int ig = tid >> 6;
  const float* vbase = Bq + (size_t)(2 * CDIM + h * CH) * HW + p;
  float acc[12] = {};
  for (int j0 = 0; j0 < 48; j0 += 4) {
    float vj[4];
#pragma unroll
    for (int q = 0; q < 4; q++) vj[q] = vbase[(size_t)(j0 + q) * HW];
#pragma unroll
    for (int ii = 0; ii < 12; ii++) {
      const float4 w4 = *reinterpret_cast<const float4*>(&Wl[(ig * 12 + ii) * 48 + j0]);
      acc[ii] += w4.x * vj[0] + w4.y * vj[1] + w4.z * vj[2] + w4.w * vj[3];
    }
  }
  float* obase = Cbuf + (size_t)(h * CH + ig * 12) * HW + p;
#pragma unroll
  for (int ii = 0; ii < 12; ii++) obase[(size_t)ii * HW] = acc[ii];
}

// ---- window attention; P stored bf16 (LDS 33.3 KB => 4 blocks/CU) ----
__global__ __launch_bounds__(256) void spatial_kernel(
    const float* __restrict__ Bq, const float* __restrict__ temp,
    const float* __restrict__ a1, const float* __restrict__ a2,
    const float* __restrict__ a3, const float* __restrict__ a4,
    float* __restrict__ Cbuf) {
  __shared__ float kL[64 * 49];
  __shared__ float qvL[64 * 49];
  __shared__ bf16 Pld[64 * 66];
  __shared__ float invqS[64], invkS[64];
  const int wid = blockIdx.x;  // head*256 + wy*16 + wx
  const int wx = wid & 15, wy = (wid >> 4) & 15;
  const int head = wid >> 8;
  const int tid = threadIdx.x;
  for (int s = tid; s < 2 * 3072; s += 256) {
    const int t = s / 3072;
    const int r = s % 3072;
    const int cc = r >> 6, n = r & 63;
    const int y = wy * 8 + (n >> 3), x = wx * 8 + (n & 7);
    const int chan = t * CDIM + head * CH + cc;
    (t ? kL : qvL)[n * 49 + cc] = Bq[(size_t)chan * HW + y * 128 + x];
  }
  __syncthreads();
  if (tid < 128) {
    const int t = tid >> 6, n = tid & 63;
    const float* src = t ? kL : qvL;
    float s = 0.f;
    for (int cc = 0; cc < 48; cc++) {
      float v = src[n * 49 + cc];
      s += v * v;
    }
    float iv = 1.f / fmaxf(sqrtf(s), 1e-12f);
    if (t) invkS[n] = iv; else invqS[n] = iv;
  }
  __syncthreads();
  const float tscale = temp[wx & 7];
  const float wts[4] = {a1[0], a2[0], a3[0], a4[0]};
  const int ksel[4] = {32, 42, 48, 51};
  const int lane = tid & 63, w = tid >> 6;
  const float ik = invkS[lane];
  for (int g = 0; g < 4; g++) {
    const int n0 = w * 16 + g * 4;
    float accr[4] = {0.f, 0.f, 0.f, 0.f};
    for (int cc = 0; cc < 48; cc++) {
      const float kv = kL[lane * 49 + cc];
#pragma unroll
      for (int r = 0; r < 4; r++) accr[r] += qvL[(n0 + r) * 49 + cc] * kv;
    }
#pragma unroll
    for (int r = 0; r < 4; r++) {
      const int n = n0 + r;
      const float a = accr[r] * invqS[n] * ik * tscale;
      float s = a;  // bitonic ascending sort across 64 lanes
#pragma unroll
      for (int k = 2; k <= 64; k <<= 1) {
#pragma unroll
        for (int j = k >> 1; j > 0; j >>= 1) {
          const float o = __shfl_xor(s, j);
          const bool up = ((lane & k) == 0);
          const bool lower = ((lane & j) == 0);
          const float mn = fminf(s, o), mx = fmaxf(s, o);
          s = (lower == up) ? mn : mx;
        }
      }
      const float m = __shfl(s, 63);
      const float e = expf(a - m);
      float coef = 0.f;
#pragma unroll
      for (int kk = 0; kk < 4; kk++) {
        const float tk = __shfl(s, 64 - ksel[kk]);
        const bool keep = (a >= tk);
        float sel = keep ? e : 0.f;
        for (int o = 32; o; o >>= 1) sel += __shfl_xor(sel, o);
        if (keep) coef += wts[kk] / sel;
      }
      Pld[n * 66 + lane] = __float2bfloat16(e * coef);
    }
  }
  __syncthreads();
  // load v over q (dead)
  for (int s = tid; s < 3072; s += 256) {
    const int cc = s >> 6, n = s & 63;
    const int y = wy * 8 + (n >> 3), x = wx * 8 + (n & 7);
    const int chan = 2 * CDIM + head * CH + cc;
    qvL[n * 49 + cc] = Bq[(size_t)chan * HW + y * 128 + x];
  }
  __syncthreads();
  const int n = lane, cg = w;
  float acc[12] = {};
  for (int mm = 0; mm < 64; mm++) {
    const float pv = __bfloat162float(Pld[n * 66 + mm]);
#pragma unroll
    for (int ci = 0; ci < 12; ci++) acc[ci] += pv * qvL[mm * 49 + cg + ci * 4];
  }
  const int y_out = wy * 8 + (wx >> 1);
  const int x_out = (wx & 1) * 64 + n;
#pragma unroll
  for (int ci = 0; ci < 12; ci++) {
    const int cc = cg + ci * 4;
    const size_t idx = ((size_t)(head * CH + cc) * 128 + y_out) * 128 + x_out;
    Cbuf[idx] += acc[ci];
  }
}

// ---------------- launch ----------------
extern "C" void kernel_launch(void* const* d_in, const int* in_sizes, int n_in,
                              void* d_out, int out_size, void* d_ws, size_t ws_size,
                              hipStream_t stream) {
  const float* x = (const float*)d_in[0];
  const float* w_qkv = (const float*)d_in[1];
  const float* w_dw = (const float*)d_in[2];
  const float* w_proj = (const float*)d_in[3];
  const float* temp = (const float*)d_in[4];
  const float* a1 = (const float*)d_in[5];
  const float* a2 = (const float*)d_in[6];
  const float* a3 = (const float*)d_in[7];
  const float* a4 = (const float*)d_in[8];
  float* out = (float*)d_out;

  // ws layout (bytes):
  //   [0,        1179648)  cattn_part f32 (16*8*2304)
  //   [1179648,  1253376)  raw f32 (8*2304)
  //   [1253376,  1327104)  W48 f32
  //   [1327104,  1330176)  inv f32 (768)
  //   [1330432,  2215168)  wqkv_h bf16 bits (1152x384)
  //   [2215168,  3099904)  wqkv_l
  //   [3099904,  3394816)  wproj_h (384x384)
  //   [3394816,  3689728)  wproj_l
  //   [3690496, 79188000~) Bq f32 (1152x16384) = 75.5 MB
  //     Xtg hi/lo in Bq v-third during qkv phase; Ctg hi/lo in q-third for proj.
  // Peak ~79.2 MB (<= proven 89.4 MB).
  char* ws = (char*)d_ws;
  float* cattn_part = (float*)ws;
  float* raw = (float*)(ws + 1179648);
  float* W48 = (float*)(ws + 1253376);
  float* inv = (float*)(ws + 1327104);
  unsigned short* wqkv_h = (unsigned short*)(ws + 1330432);
  unsigned short* wqkv_l = (unsigned short*)(ws + 2215168);
  unsigned short* wproj_h = (unsigned short*)(ws + 3099904);
  unsigned short* wproj_l = (unsigned short*)(ws + 3394816);
  float* Bq = (float*)(ws + 3690496);
  short8* Xtgh = (short8*)(ws + 3690496 + (size_t)2 * CDIM * HW * 4);
  short8* Xtgl = (short8*)(ws + 3690496 + (size_t)2 * CDIM * HW * 4 + 12582912);
  short8* Ctgh = (short8*)(ws + 3690496);
  short8* Ctgl = (short8*)(ws + 3690496 + 12582912);

  decomp_w<<<(3 * CDIM * CDIM + 255) / 256, 256, 0, stream>>>(w_qkv, wqkv_h, wqkv_l,
                                                              3 * CDIM * CDIM);
  decomp_w<<<(CDIM * CDIM + 255) / 256, 256, 0, stream>>>(w_proj, wproj_h, wproj_l,
                                                          CDIM * CDIM);

  for (int b = 0; b < 2; b++) {
    const float* xb = x + (size_t)b * CDIM * HW;
    float* ob = out + (size_t)b * CDIM * HW;  // scratch (conv1 out / Cbuf) then final

    // x -> fragment-order hi/lo (in Bq v-third, dead until dwconv t=2)
    transpose_frag<<<3072, 256, 0, stream>>>(xb, Xtgh, Xtgl);
    for (int t = 0; t < 3; t++) {
      gemm_mfma<<<dim3(HW / 128, CDIM / 64), 256, 0, stream>>>(
          wqkv_h + (size_t)t * CDIM * CDIM, wqkv_l + (size_t)t * CDIM * CDIM,
          Xtgh, Xtgl, ob);
      dwconv3<<<(CDIM * HW) / 256, 256, 0, stream>>>(
          ob, w_dw + (size_t)t * CDIM * 9, Bq + (size_t)t * CDIM * HW);
    }

    chan_norms<<<2 * CDIM, 256, 0, stream>>>(Bq, inv);
    cattn_partial<<<dim3(16, NHEADS), 256, 0, stream>>>(Bq, cattn_part);
    cattn_reduce<<<NHEADS, 256, 0, stream>>>(cattn_part, raw);
    chan_softmax<<<NHEADS * 48, 64, 0, stream>>>(raw, inv, temp, a1, a2, a3, a4, W48);
    cout_kernel<<<dim3(HW / 64, NHEADS), 256, 0, stream>>>(W48, Bq, ob);
    spatial_kernel<<<NHEADS * 256, 256, 0, stream>>>(Bq, temp, a1, a2, a3, a4, ob);

    // proj: Cbuf(=ob) -> frag-order hi/lo in Bq q-third (dead), gemm -> ob
    transpose_frag<<<3072, 256, 0, stream>>>(ob, Ctgh, Ctgl);
    gemm_mfma<<<dim3(HW / 128, CDIM / 64), 256, 0, stream>>>(wproj_h, wproj_l,
                                                             Ctgh, Ctgl, ob);
  }

  (void)in_sizes; (void)n_in; (void)out_size; (void)ws_size;
}